// Round 4
// baseline (324.045 us; speedup 1.0000x reference)
//
#include <hip/hip_runtime.h>
#include <math.h>

#define N_POS 8000
#define C_CH  128
#define KSPLIT 5
#define KT_PER 25      // 125 k-tiles of 64 keys, 25 per split

typedef __bf16 bf16x8 __attribute__((ext_vector_type(8)));
typedef float  f32x4  __attribute__((ext_vector_type(4)));

#define MFMA(a,b,c) __builtin_amdgcn_mfma_f32_16x16x32_bf16((a),(b),(c),0,0,0)

// MFMA 16x16x32 lane layouts (verified m89/m120):
//   A[m][k]: m = lane&15, k = (lane>>4)*8 + j
//   B[k][n]: n = lane&15, k = (lane>>4)*8 + j
//   D[m][n]: n = lane&15, m = (lane>>4)*4 + reg

// ---------------------------------------------------------------------------
// Kernel A: QKV projections via MFMA. grid 500: nt = bx>>1 (32-n tile),
// h = bx&1 selects output half (mtiles h*5 .. h*5+4 of 10).
// ---------------------------------------------------------------------------
__global__ __launch_bounds__(256) void qkv_kernel(
    const float* __restrict__ x,
    const float* __restrict__ wq, const float* __restrict__ bq,
    const float* __restrict__ wk, const float* __restrict__ bk,
    const float* __restrict__ wv, const float* __restrict__ bv,
    __bf16* __restrict__ q_bf, __bf16* __restrict__ k_bf, __bf16* __restrict__ v_bf)
{
    __shared__ __bf16 x_lds[32 * 136];          // [n][c]
    __shared__ __bf16 v_out[80 * 36];           // [local v-ch][n]

    const int t    = threadIdx.x;
    const int nt   = blockIdx.x >> 1;
    const int h    = blockIdx.x & 1;
    const int n0   = nt * 32;
    const int lane = t & 63;
    const int w    = t >> 6;
    const int l15  = lane & 15;
    const int quad = lane >> 4;

    // stage x tile [128c x 32n] -> x_lds[n][c] bf16
    for (int r = 0; r < 4; ++r) {
        int f = r * 256 + t;
        int ch = f >> 3, n4 = f & 7;
        float4 xv = *reinterpret_cast<const float4*>(&x[ch * N_POS + n0 + n4 * 4]);
        x_lds[(n4 * 4 + 0) * 136 + ch] = (__bf16)xv.x;
        x_lds[(n4 * 4 + 1) * 136 + ch] = (__bf16)xv.y;
        x_lds[(n4 * 4 + 2) * 136 + ch] = (__bf16)xv.z;
        x_lds[(n4 * 4 + 3) * 136 + ch] = (__bf16)xv.w;
    }

    const int nmt = (w == 0) ? 2 : 1;
    int mts[2] = { h * 5 + w, h * 5 + 4 };

    bf16x8 aw[2][4];
    f32x4  acc[2][2];
    for (int mi = 0; mi < nmt; ++mi) {
        int mt = mts[mi];
        const float *wrow, *brow;
        if (mt == 0)      { wrow = wq + l15 * 128;               brow = bq; }
        else if (mt == 1) { wrow = wk + l15 * 128;               brow = bk; }
        else              { wrow = wv + ((mt - 2) * 16 + l15) * 128;
                            brow = bv + (mt - 2) * 16; }
        for (int ks = 0; ks < 4; ++ks) {
            float4 f0 = *reinterpret_cast<const float4*>(wrow + ks * 32 + quad * 8);
            float4 f1 = *reinterpret_cast<const float4*>(wrow + ks * 32 + quad * 8 + 4);
            bf16x8 a;
            a[0]=(__bf16)f0.x; a[1]=(__bf16)f0.y; a[2]=(__bf16)f0.z; a[3]=(__bf16)f0.w;
            a[4]=(__bf16)f1.x; a[5]=(__bf16)f1.y; a[6]=(__bf16)f1.z; a[7]=(__bf16)f1.w;
            aw[mi][ks] = a;
        }
        for (int ni = 0; ni < 2; ++ni) {
            acc[mi][ni][0] = brow[quad * 4 + 0]; acc[mi][ni][1] = brow[quad * 4 + 1];
            acc[mi][ni][2] = brow[quad * 4 + 2]; acc[mi][ni][3] = brow[quad * 4 + 3];
        }
    }
    __syncthreads();

    for (int ks = 0; ks < 4; ++ks) {
        bf16x8 b0 = *reinterpret_cast<const bf16x8*>(&x_lds[(0  + l15) * 136 + ks * 32 + quad * 8]);
        bf16x8 b1 = *reinterpret_cast<const bf16x8*>(&x_lds[(16 + l15) * 136 + ks * 32 + quad * 8]);
        for (int mi = 0; mi < nmt; ++mi) {
            acc[mi][0] = MFMA(aw[mi][ks], b0, acc[mi][0]);
            acc[mi][1] = MFMA(aw[mi][ks], b1, acc[mi][1]);
        }
    }

    union S4 { short4 s; __bf16 b[4]; };
    for (int mi = 0; mi < nmt; ++mi) {
        int mt = mts[mi];
        for (int ni = 0; ni < 2; ++ni) {
            S4 u;
            u.b[0]=(__bf16)acc[mi][ni][0]; u.b[1]=(__bf16)acc[mi][ni][1];
            u.b[2]=(__bf16)acc[mi][ni][2]; u.b[3]=(__bf16)acc[mi][ni][3];
            int n = n0 + ni * 16 + l15;
            if (mt == 0) {
                *reinterpret_cast<short4*>(&q_bf[n * 16 + quad * 4]) = u.s;
            } else if (mt == 1) {
                *reinterpret_cast<short4*>(&k_bf[n * 16 + quad * 4]) = u.s;
            } else {
                int lv = (mt - 2) * 16 - h * 48 + quad * 4;
                int nl = ni * 16 + l15;
                v_out[(lv + 0) * 36 + nl] = u.b[0];
                v_out[(lv + 1) * 36 + nl] = u.b[1];
                v_out[(lv + 2) * 36 + nl] = u.b[2];
                v_out[(lv + 3) * 36 + nl] = u.b[3];
            }
        }
    }
    __syncthreads();
    const int nch = h ? 80 : 48;
    for (int f = t; f < nch * 8; f += 256) {
        int lc = f >> 3, n4 = f & 7;
        int2 d = *reinterpret_cast<const int2*>(&v_out[lc * 36 + n4 * 4]);
        *reinterpret_cast<int2*>(&v_bf[(lc + h * 48) * N_POS + n0 + n4 * 4]) = d;
    }
}

// ---------------------------------------------------------------------------
// Kernel B: fused attention, split-K, MFMA, register-prefetch pipeline.
// S phase transposed (A=K, B=Q) so each thread's 4 P values are 4 consecutive
// keys -> one ds_write_b64.  All LDS tiles fragment-packed (lane-contiguous
// 16B chunks, XOR-swizzled where writer/reader lane maps differ).
// grid 1250 (qt = b%250 -> 32 queries, sp = b/250 -> 25 k-tiles of 64).
// ---------------------------------------------------------------------------
__global__ __launch_bounds__(256) void attn_kernel(
    const __bf16* __restrict__ q_bf, const __bf16* __restrict__ k_bf,
    const __bf16* __restrict__ v_bf, float* __restrict__ av_part,
    float* __restrict__ l_part)
{
    __shared__ __bf16 k_lds[64 * 32];   // [key][dim], dims 16..31 stay zero
    __shared__ __bf16 v_lds[8192];      // fragment-packed: chunk=((ct*2+ks)*4+qd)*16+(l15^(qd*2+ks))
    __shared__ __bf16 p_lds[2048];      // fragment-packed: chunk=(ni*2+ks)*64+quad*16+l15

    const int t    = threadIdx.x;
    const int qt   = blockIdx.x % 250;
    const int sp   = blockIdx.x / 250;
    const int n0q  = qt * 32;
    const int lane = t & 63;
    const int w    = t >> 6;
    const int l15  = lane & 15;
    const int quad = lane >> 4;

    // zero pad dims 16..31 of k_lds once (never overwritten)
    for (int f = t; f < 64 * 16; f += 256) {
        int key = f >> 4, d = 16 + (f & 15);
        k_lds[key * 32 + d] = (__bf16)0.0f;
    }

    // V staging map: thread handles ch = r*32 + (t>>3), keys part*8.. (part=t&7)
    const int vch  = t >> 3;
    const int vpart = t & 7;
    const int vks = vpart >> 2, vqd = vpart & 3;

    // Q B-frags in registers (k-dim 16 padded to 32 with zeros)
    bf16x8 aq[2];
    for (int ni = 0; ni < 2; ++ni) {
        if (quad < 2) {
            aq[ni] = *reinterpret_cast<const bf16x8*>(
                &q_bf[(n0q + ni * 16 + l15) * 16 + quad * 8]);
        } else {
            for (int j = 0; j < 8; ++j) aq[ni][j] = (__bf16)0.0f;
        }
    }
    bf16x8 ones;
    for (int j = 0; j < 8; ++j) ones[j] = (__bf16)1.0f;

    f32x4 acc[2][2];
    for (int mi = 0; mi < 2; ++mi)
        for (int ni = 0; ni < 2; ++ni)
            for (int r = 0; r < 4; ++r) acc[mi][ni][r] = 0.f;
    f32x4 lacc[2];
    for (int ni = 0; ni < 2; ++ni)
        for (int r = 0; r < 4; ++r) lacc[ni][r] = 0.f;

    const int kt0 = sp * KT_PER;

    // preload tile kt0 into registers
    int4 vpre[4];
    int4 kpre;
    {
        const int n0k = kt0 * 64;
        for (int r = 0; r < 4; ++r)
            vpre[r] = *reinterpret_cast<const int4*>(
                &v_bf[(r * 32 + vch) * N_POS + n0k + vpart * 8]);
        if (t < 128)
            kpre = *reinterpret_cast<const int4*>(
                &k_bf[(n0k + (t >> 1)) * 16 + (t & 1) * 8]);
    }

    const int ksS    = w >> 1;                      // P-write chunk coords
    const int quad_r = (w & 1) * 2 + (quad >> 1);
    const int j0     = (quad & 1) * 4;

    for (int kt = kt0; kt < kt0 + KT_PER; ++kt) {
        __syncthreads();   // all reads of previous tile done
        // commit staged registers -> LDS
        for (int r = 0; r < 4; ++r) {
            int ch = r * 32 + vch;
            int chunk = (((ch >> 4) * 2 + vks) * 4 + vqd) * 16 + ((ch & 15) ^ (vqd * 2 + vks));
            *reinterpret_cast<int4*>(&v_lds[chunk * 8]) = vpre[r];
        }
        if (t < 128)
            *reinterpret_cast<int4*>(&k_lds[(t >> 1) * 32 + (t & 1) * 8]) = kpre;
        __syncthreads();

        // ---- S phase: A = K rows (wave w -> keys w*16..+15), B = Q regs
        bf16x8 ak = *reinterpret_cast<const bf16x8*>(&k_lds[(w * 16 + l15) * 32 + quad * 8]);
        f32x4 s0, s1;
        for (int r = 0; r < 4; ++r) { s0[r] = 0.f; s1[r] = 0.f; }
        s0 = MFMA(ak, aq[0], s0);   // D[m=key][n=q]
        s1 = MFMA(ak, aq[1], s1);
        union S4 { short4 sh; __bf16 b[4]; };
        {
            S4 u;
            u.b[0] = (__bf16)__expf(s0[0]); u.b[1] = (__bf16)__expf(s0[1]);
            u.b[2] = (__bf16)__expf(s0[2]); u.b[3] = (__bf16)__expf(s0[3]);
            *reinterpret_cast<short4*>(&p_lds[((0 + ksS) * 64 + quad_r * 16 + l15) * 8 + j0]) = u.sh;
            u.b[0] = (__bf16)__expf(s1[0]); u.b[1] = (__bf16)__expf(s1[1]);
            u.b[2] = (__bf16)__expf(s1[2]); u.b[3] = (__bf16)__expf(s1[3]);
            *reinterpret_cast<short4*>(&p_lds[((2 + ksS) * 64 + quad_r * 16 + l15) * 8 + j0]) = u.sh;
        }
        __syncthreads();

        // ---- prefetch next tile into registers (drains at next top barrier,
        //      hidden under the PV phase below)
        {
            int ktn = (kt + 1 < kt0 + KT_PER) ? kt + 1 : kt0;
            const int n0k = ktn * 64;
            for (int r = 0; r < 4; ++r)
                vpre[r] = *reinterpret_cast<const int4*>(
                    &v_bf[(r * 32 + vch) * N_POS + n0k + vpart * 8]);
            if (t < 128)
                kpre = *reinterpret_cast<const int4*>(
                    &k_bf[(n0k + (t >> 1)) * 16 + (t & 1) * 8]);
        }

        // ---- PV phase: wave w owns ch-tiles {2w, 2w+1}
        for (int ks = 0; ks < 2; ++ks) {
            bf16x8 a0 = *reinterpret_cast<const bf16x8*>(
                &v_lds[((((2 * w)     * 2 + ks) * 4 + quad) * 16 + (l15 ^ (quad * 2 + ks))) * 8]);
            bf16x8 a1 = *reinterpret_cast<const bf16x8*>(
                &v_lds[((((2 * w + 1) * 2 + ks) * 4 + quad) * 16 + (l15 ^ (quad * 2 + ks))) * 8]);
            bf16x8 p0 = *reinterpret_cast<const bf16x8*>(
                &p_lds[((0 + ks) * 64 + quad * 16 + l15) * 8]);
            bf16x8 p1 = *reinterpret_cast<const bf16x8*>(
                &p_lds[((2 + ks) * 64 + quad * 16 + l15) * 8]);
            acc[0][0] = MFMA(a0, p0, acc[0][0]);
            acc[0][1] = MFMA(a0, p1, acc[0][1]);
            acc[1][0] = MFMA(a1, p0, acc[1][0]);
            acc[1][1] = MFMA(a1, p1, acc[1][1]);
            if (w == 0) {
                lacc[0] = MFMA(ones, p0, lacc[0]);
                lacc[1] = MFMA(ones, p1, lacc[1]);
            }
        }
    }

    // write av partials: av_part[sp][n][c] fp32
    float* dst = av_part + (size_t)sp * 1024000;
    for (int mi = 0; mi < 2; ++mi)
        for (int ni = 0; ni < 2; ++ni) {
            int n  = n0q + ni * 16 + l15;
            int ch = (2 * w + mi) * 16 + quad * 4;
            *reinterpret_cast<f32x4*>(&dst[n * 128 + ch]) = acc[mi][ni];
        }
    if (w == 0 && quad == 0) {
        l_part[sp * N_POS + n0q + 0  + l15] = lacc[0][0];
        l_part[sp * N_POS + n0q + 16 + l15] = lacc[1][0];
    }
}

// ---------------------------------------------------------------------------
// Kernel C: split-K reduce + normalize (in LDS, fp32) fused with
// y = wa @ av + ba (MFMA) + BN stats.  grid 500: nt = bx>>1, h = bx&1
// (mtiles h*4 .. h*4+3; one mtile per wave).
// ---------------------------------------------------------------------------
__global__ __launch_bounds__(256) void proj_out_kernel(
    const float* __restrict__ av_part, const float* __restrict__ l_part,
    const float* __restrict__ wa, const float* __restrict__ ba,
    float* __restrict__ y_ws, float* __restrict__ bn_sum, float* __restrict__ bn_sumsq)
{
    __shared__ __bf16 b_lds[4096];   // 32n x 128c fragment-packed, swizzled

    const int t    = threadIdx.x;
    const int nt   = blockIdx.x >> 1;
    const int h    = blockIdx.x & 1;
    const int n0   = nt * 32;
    const int lane = t & 63;
    const int w    = t >> 6;
    const int l15  = lane & 15;
    const int quad = lane >> 4;

    // build normalized B tile: 512 c-octets, 2 per thread (coalesced reads)
    for (int r = 0; r < 2; ++r) {
        int g = r * 256 + t;
        int n = g >> 4, oc = g & 15;
        float l = 0.f;
#pragma unroll
        for (int s = 0; s < KSPLIT; ++s) l += l_part[s * N_POS + n0 + n];
        float4 a0 = make_float4(0.f, 0.f, 0.f, 0.f);
        float4 a1 = make_float4(0.f, 0.f, 0.f, 0.f);
#pragma unroll
        for (int s = 0; s < KSPLIT; ++s) {
            const float* p = av_part + (size_t)s * 1024000 + (n0 + n) * 128 + oc * 8;
            float4 u = *reinterpret_cast<const float4*>(p);
            float4 v = *reinterpret_cast<const float4*>(p + 4);
            a0.x += u.x; a0.y += u.y; a0.z += u.z; a0.w += u.w;
            a1.x += v.x; a1.y += v.y; a1.z += v.z; a1.w += v.w;
        }
        float inv = 1.f / l;
        union { int4 iv; __bf16 b[8]; } u;
        u.b[0]=(__bf16)(a0.x*inv); u.b[1]=(__bf16)(a0.y*inv);
        u.b[2]=(__bf16)(a0.z*inv); u.b[3]=(__bf16)(a0.w*inv);
        u.b[4]=(__bf16)(a1.x*inv); u.b[5]=(__bf16)(a1.y*inv);
        u.b[6]=(__bf16)(a1.z*inv); u.b[7]=(__bf16)(a1.w*inv);
        int A = (n >> 4) * 16 + oc;
        int slot = (n & 15) ^ (oc & 7);
        *reinterpret_cast<int4*>(&b_lds[(A * 16 + slot) * 8]) = u.iv;
    }

    // A-frags: wa rows for this wave's mtile
    const int mt = h * 4 + w;
    bf16x8 aw[4];
    const float* wrow = wa + (mt * 16 + l15) * 128;
    for (int ks = 0; ks < 4; ++ks) {
        float4 f0 = *reinterpret_cast<const float4*>(wrow + ks * 32 + quad * 8);
        float4 f1 = *reinterpret_cast<const float4*>(wrow + ks * 32 + quad * 8 + 4);
        bf16x8 a;
        a[0]=(__bf16)f0.x; a[1]=(__bf16)f0.y; a[2]=(__bf16)f0.z; a[3]=(__bf16)f0.w;
        a[4]=(__bf16)f1.x; a[5]=(__bf16)f1.y; a[6]=(__bf16)f1.z; a[7]=(__bf16)f1.w;
        aw[ks] = a;
    }
    f32x4 acc[2];
    for (int ni = 0; ni < 2; ++ni) {
        acc[ni][0] = ba[mt * 16 + quad * 4 + 0];
        acc[ni][1] = ba[mt * 16 + quad * 4 + 1];
        acc[ni][2] = ba[mt * 16 + quad * 4 + 2];
        acc[ni][3] = ba[mt * 16 + quad * 4 + 3];
    }
    __syncthreads();

    for (int ks = 0; ks < 4; ++ks) {
        int oc = ks * 4 + quad;
        int slot = l15 ^ (oc & 7);
        bf16x8 b0 = *reinterpret_cast<const bf16x8*>(&b_lds[((0  + oc) * 16 + slot) * 8]);
        bf16x8 b1 = *reinterpret_cast<const bf16x8*>(&b_lds[((16 + oc) * 16 + slot) * 8]);
        acc[0] = MFMA(aw[ks], b0, acc[0]);
        acc[1] = MFMA(aw[ks], b1, acc[1]);
    }

    // y writes [c][n] + BN partial stats
    for (int r = 0; r < 4; ++r) {
        int ch = mt * 16 + quad * 4 + r;
        float v0 = acc[0][r];
        float v1 = acc[1][r];
        y_ws[ch * N_POS + n0 + 0  + l15] = v0;
        y_ws[ch * N_POS + n0 + 16 + l15] = v1;
        float s1 = v0 + v1;
        float s2 = v0 * v0 + v1 * v1;
#pragma unroll
        for (int off = 8; off >= 1; off >>= 1) {
            s1 += __shfl_xor(s1, off, 64);
            s2 += __shfl_xor(s2, off, 64);
        }
        if (l15 == 0) {
            atomicAdd(&bn_sum[ch],   s1);
            atomicAdd(&bn_sumsq[ch], s2);
        }
    }
}

// ---------------------------------------------------------------------------
// Kernel D: BatchNorm (training stats) + ReLU + residual. grid 1000, block 256.
// ---------------------------------------------------------------------------
__global__ __launch_bounds__(256) void bn_relu_kernel(
    const float* __restrict__ y_ws, const float* __restrict__ x,
    const float* __restrict__ bn_sum, const float* __restrict__ bn_sumsq,
    const float* __restrict__ bn_w, const float* __restrict__ bn_b,
    float* __restrict__ out)
{
    const int i4 = blockIdx.x * 256 + threadIdx.x;
    const int c  = i4 / 2000;
    const float mean  = bn_sum[c]   * (1.f / 8000.f);
    const float var   = bn_sumsq[c] * (1.f / 8000.f) - mean * mean;
    const float rstd  = rsqrtf(var + 1e-5f);
    const float scale = bn_w[c] * rstd;
    const float shift = bn_b[c] - mean * scale;

    float4 y4 = reinterpret_cast<const float4*>(y_ws)[i4];
    float4 x4 = reinterpret_cast<const float4*>(x)[i4];
    float4 o4;
    o4.x = fmaxf(y4.x * scale + shift, 0.f) + x4.x;
    o4.y = fmaxf(y4.y * scale + shift, 0.f) + x4.y;
    o4.z = fmaxf(y4.z * scale + shift, 0.f) + x4.z;
    o4.w = fmaxf(y4.w * scale + shift, 0.f) + x4.w;
    reinterpret_cast<float4*>(out)[i4] = o4;
}

// ---------------------------------------------------------------------------
extern "C" void kernel_launch(void* const* d_in, const int* in_sizes, int n_in,
                              void* d_out, int out_size, void* d_ws, size_t ws_size,
                              hipStream_t stream)
{
    const float* x    = (const float*)d_in[0];
    const float* wq   = (const float*)d_in[1];
    const float* bq   = (const float*)d_in[2];
    const float* wk   = (const float*)d_in[3];
    const float* bk   = (const float*)d_in[4];
    const float* wv   = (const float*)d_in[5];
    const float* bv   = (const float*)d_in[6];
    const float* wa   = (const float*)d_in[7];
    const float* ba   = (const float*)d_in[8];
    const float* bn_w = (const float*)d_in[9];
    const float* bn_b = (const float*)d_in[10];
    float* out = (float*)d_out;

    char* base = (char*)d_ws;
    // byte layout (~27.3 MB):
    float*  av_part = (float*)base;                    // 20,480,000 B (5 x 8000 x 128 f32)
    __bf16* q_bf    = (__bf16*)(base + 20480000);      //    256,000 B
    __bf16* k_bf    = (__bf16*)(base + 20736000);      //    256,000 B
    __bf16* v_bf    = (__bf16*)(base + 20992000);      //  2,048,000 B
    float*  l_part  = (float*)(base + 23040000);       //    160,000 B
    float*  bn_sum   = (float*)(base + 23200000);      //        512 B
    float*  bn_sumsq = bn_sum + 128;                   //        512 B
    float*  y_ws    = (float*)(base + 23201024);       //  4,096,000 B

    hipMemsetAsync(bn_sum, 0, 1024, stream);
    qkv_kernel<<<500, 256, 0, stream>>>(x, wq, bq, wk, bk, wv, bv, q_bf, k_bf, v_bf);
    attn_kernel<<<250 * KSPLIT, 256, 0, stream>>>(q_bf, k_bf, v_bf, av_part, l_part);
    proj_out_kernel<<<500, 256, 0, stream>>>(av_part, l_part, wa, ba, y_ws, bn_sum, bn_sumsq);
    bn_relu_kernel<<<1000, 256, 0, stream>>>(y_ws, x, bn_sum, bn_sumsq, bn_w, bn_b, out);
}

// Round 5
// 177.408 us; speedup vs baseline: 1.8265x; 1.8265x over previous
//
#include <hip/hip_runtime.h>
#include <math.h>

#define N_POS 8000
#define C_CH  128
#define KSPLIT 5
#define KT_PER 25      // 125 k-tiles of 64 keys, 25 per split

typedef __bf16 bf16x8 __attribute__((ext_vector_type(8)));
typedef float  f32x4  __attribute__((ext_vector_type(4)));

#define MFMA(a,b,c) __builtin_amdgcn_mfma_f32_16x16x32_bf16((a),(b),(c),0,0,0)

// MFMA 16x16x32 lane layouts (verified m89/m120):
//   A[m][k]: m = lane&15, k = (lane>>4)*8 + j
//   B[k][n]: n = lane&15, k = (lane>>4)*8 + j
//   D[m][n]: n = lane&15, m = (lane>>4)*4 + reg

#define GLOAD_LDS(gp, lp) \
    __builtin_amdgcn_global_load_lds( \
        (const __attribute__((address_space(1))) void*)(gp), \
        (__attribute__((address_space(3))) void*)(lp), 16, 0, 0)

// ---------------------------------------------------------------------------
// Kernel A: QKV projections via MFMA. grid 250 (n-tiles of 32), block 256.
// out rows: o 0..15 -> q, 16..31 -> k, 32..159 -> v(ch=o-32)
// q_bf,k_bf: [n][16] bf16.  v_bf: [c][8000] bf16.
// ---------------------------------------------------------------------------
__global__ __launch_bounds__(256) void qkv_kernel(
    const float* __restrict__ x,
    const float* __restrict__ wq, const float* __restrict__ bq,
    const float* __restrict__ wk, const float* __restrict__ bk,
    const float* __restrict__ wv, const float* __restrict__ bv,
    __bf16* __restrict__ q_bf, __bf16* __restrict__ k_bf, __bf16* __restrict__ v_bf)
{
    __shared__ __bf16 x_lds[32 * 136];          // [n][c]
    __shared__ __bf16 v_out[128 * 36];          // [ch][n]

    const int t    = threadIdx.x;
    const int n0   = blockIdx.x * 32;
    const int lane = t & 63;
    const int w    = t >> 6;
    const int l15  = lane & 15;
    const int quad = lane >> 4;

    // stage x tile [128c x 32n] -> x_lds[n][c] bf16 (transpose+convert)
    for (int r = 0; r < 4; ++r) {
        int f = r * 256 + t;
        int ch = f >> 3, n4 = f & 7;
        float4 xv = *reinterpret_cast<const float4*>(&x[ch * N_POS + n0 + n4 * 4]);
        x_lds[(n4 * 4 + 0) * 136 + ch] = (__bf16)xv.x;
        x_lds[(n4 * 4 + 1) * 136 + ch] = (__bf16)xv.y;
        x_lds[(n4 * 4 + 2) * 136 + ch] = (__bf16)xv.z;
        x_lds[(n4 * 4 + 3) * 136 + ch] = (__bf16)xv.w;
    }

    // A-frags: weight rows fp32->bf16 in regs. wave w owns mtiles {w, w+4, w+8<10}
    bf16x8 aw[3][4];
    f32x4  acc[3][2];
    const int nmt = (w < 2) ? 3 : 2;
    for (int mi = 0; mi < nmt; ++mi) {
        int mt = w + 4 * mi;
        const float *wrow, *brow;
        if (mt == 0)      { wrow = wq + l15 * 128;               brow = bq; }
        else if (mt == 1) { wrow = wk + l15 * 128;               brow = bk; }
        else              { wrow = wv + ((mt - 2) * 16 + l15) * 128;
                            brow = bv + (mt - 2) * 16; }
        for (int ks = 0; ks < 4; ++ks) {
            float4 f0 = *reinterpret_cast<const float4*>(wrow + ks * 32 + quad * 8);
            float4 f1 = *reinterpret_cast<const float4*>(wrow + ks * 32 + quad * 8 + 4);
            bf16x8 a;
            a[0]=(__bf16)f0.x; a[1]=(__bf16)f0.y; a[2]=(__bf16)f0.z; a[3]=(__bf16)f0.w;
            a[4]=(__bf16)f1.x; a[5]=(__bf16)f1.y; a[6]=(__bf16)f1.z; a[7]=(__bf16)f1.w;
            aw[mi][ks] = a;
        }
        for (int ni = 0; ni < 2; ++ni) {
            acc[mi][ni][0] = brow[quad * 4 + 0]; acc[mi][ni][1] = brow[quad * 4 + 1];
            acc[mi][ni][2] = brow[quad * 4 + 2]; acc[mi][ni][3] = brow[quad * 4 + 3];
        }
    }
    __syncthreads();

    for (int ks = 0; ks < 4; ++ks) {
        bf16x8 b0 = *reinterpret_cast<const bf16x8*>(&x_lds[(0  + l15) * 136 + ks * 32 + quad * 8]);
        bf16x8 b1 = *reinterpret_cast<const bf16x8*>(&x_lds[(16 + l15) * 136 + ks * 32 + quad * 8]);
        for (int mi = 0; mi < nmt; ++mi) {
            acc[mi][0] = MFMA(aw[mi][ks], b0, acc[mi][0]);
            acc[mi][1] = MFMA(aw[mi][ks], b1, acc[mi][1]);
        }
    }

    union S4 { short4 s; __bf16 b[4]; };
    for (int mi = 0; mi < nmt; ++mi) {
        int mt = w + 4 * mi;
        for (int ni = 0; ni < 2; ++ni) {
            S4 u;
            u.b[0]=(__bf16)acc[mi][ni][0]; u.b[1]=(__bf16)acc[mi][ni][1];
            u.b[2]=(__bf16)acc[mi][ni][2]; u.b[3]=(__bf16)acc[mi][ni][3];
            int n = n0 + ni * 16 + l15;
            if (mt == 0) {
                *reinterpret_cast<short4*>(&q_bf[n * 16 + quad * 4]) = u.s;
            } else if (mt == 1) {
                *reinterpret_cast<short4*>(&k_bf[n * 16 + quad * 4]) = u.s;
            } else {
                int ch0 = (mt - 2) * 16 + quad * 4;
                int nl  = ni * 16 + l15;
                v_out[(ch0 + 0) * 36 + nl] = u.b[0];
                v_out[(ch0 + 1) * 36 + nl] = u.b[1];
                v_out[(ch0 + 2) * 36 + nl] = u.b[2];
                v_out[(ch0 + 3) * 36 + nl] = u.b[3];
            }
        }
    }
    __syncthreads();
    for (int r = 0; r < 4; ++r) {
        int f = r * 256 + t;
        int ch = f >> 3, n4 = f & 7;
        int2 d = *reinterpret_cast<const int2*>(&v_out[ch * 36 + n4 * 4]);
        *reinterpret_cast<int2*>(&v_bf[ch * N_POS + n0 + n4 * 4]) = d;
    }
}

// ---------------------------------------------------------------------------
// Kernel B: fused attention, split-K, MFMA, global_load_lds double-buffer.
// DMA destinations are lane-sequential (HW requirement); the chunk maps are
// chosen so every MFMA-fragment ds_read_b128 is bank-conflict-free:
//   V chunk(ch,part) at ((ch>>3)*64 + (ch&7)*8 + (part^(ch&7)))*16B
//   K [key][dim16] contiguous (32B/key); upper k-half of A-frag zero in regs
//   P chunk(q,octet) at (octet*32 + q)*16B
// Per iter: barrier_A (cur DMA drained, issued one PV-phase ago -> cheap),
// S phase, barrier_B (nothing outstanding -> cheap), issue next DMA, PV.
// grid 1250 (qt = b%250 -> 32 queries, sp = b/250 -> 25 k-tiles of 64).
// ---------------------------------------------------------------------------
__global__ __launch_bounds__(256, 4) void attn_kernel(
    const __bf16* __restrict__ q_bf, const __bf16* __restrict__ k_bf,
    const __bf16* __restrict__ v_bf, float* __restrict__ av_part,
    float* __restrict__ l_part)
{
    __shared__ __bf16 v_buf[2][8192];   // 16 KB each
    __shared__ __bf16 k_buf[2][1024];   // 2 KB each
    __shared__ __bf16 p_lds[2048];      // 4 KB;  total = 40960 B -> 4 blocks/CU

    const int t    = threadIdx.x;
    const int qt   = blockIdx.x % 250;
    const int sp   = blockIdx.x / 250;
    const int n0q  = qt * 32;
    const int lane = t & 63;
    const int w    = t >> 6;
    const int l15  = lane & 15;
    const int quad = lane >> 4;

    // staging maps (per lane, loop-invariant)
    const int chL   = lane >> 3;              // V: low 3 bits of channel
    const int vpart = (lane & 7) ^ chL;       // V: key-octet (XOR swizzle)
    const int kkey  = lane >> 1;              // K: key within 32-key half
    const int khalf = lane & 1;               // K: dim half

    // Q B-frags in registers (k-dim 16 padded to 32 with zeros)
    bf16x8 aq[2];
    for (int ni = 0; ni < 2; ++ni) {
        for (int j = 0; j < 8; ++j) aq[ni][j] = (__bf16)0.0f;
        if (quad < 2)
            aq[ni] = *reinterpret_cast<const bf16x8*>(
                &q_bf[(n0q + ni * 16 + l15) * 16 + quad * 8]);
    }
    bf16x8 ones;
    for (int j = 0; j < 8; ++j) ones[j] = (__bf16)1.0f;

    f32x4 acc[2][2];
    for (int mi = 0; mi < 2; ++mi)
        for (int ni = 0; ni < 2; ++ni)
            for (int r = 0; r < 4; ++r) acc[mi][ni][r] = 0.f;
    f32x4 lacc[2];
    for (int ni = 0; ni < 2; ++ni)
        for (int r = 0; r < 4; ++r) lacc[ni][r] = 0.f;

    const int kt0 = kt0 < 0 ? 0 : sp * KT_PER;   // (sp*KT_PER; keep simple)

    // issue one tile's staging DMA: 4 V ops (wave-split) + 2 K ops
    // (K issued redundantly by all 4 waves -> uniform vmcnt; identical bytes)
    auto stage = [&](int kt, int buf) {
        const int n0k = kt * 64;
        for (int r = 0; r < 4; ++r) {
            int R = w * 4 + r;   // wave-uniform LDS base
            GLOAD_LDS(v_bf + (8 * R + chL) * N_POS + n0k + vpart * 8,
                      &v_buf[buf][R * 512]);
        }
        for (int h = 0; h < 2; ++h) {
            GLOAD_LDS(k_bf + (size_t)(n0k + h * 32 + kkey) * 16 + khalf * 8,
                      &k_buf[buf][h * 512]);
        }
    };

    stage(kt0, 0);

    const int oS  = w * 2 + (quad >> 1);   // P-write octet
    const int sub = (quad & 1) * 4;        // P-write elem offset in chunk

    for (int kt = kt0; kt < kt0 + KT_PER; ++kt) {
        const int cur = (kt - kt0) & 1;
        __syncthreads();   // barrier_A: cur DMA drained; prev PV reads done

        // ---- S phase: A = K rows (wave w -> keys w*16..+15), B = Q regs
        bf16x8 ak;
        for (int j = 0; j < 8; ++j) ak[j] = (__bf16)0.0f;
        if (quad < 2)
            ak = *reinterpret_cast<const bf16x8*>(
                &k_buf[cur][(w * 16 + l15) * 16 + quad * 8]);
        f32x4 s0, s1;
        for (int r = 0; r < 4; ++r) { s0[r] = 0.f; s1[r] = 0.f; }
        s0 = MFMA(ak, aq[0], s0);   // D[m=key][n=q]
        s1 = MFMA(ak, aq[1], s1);
        union S4 { short4 sh; __bf16 b[4]; };
        {
            S4 u;
            u.b[0] = (__bf16)__expf(s0[0]); u.b[1] = (__bf16)__expf(s0[1]);
            u.b[2] = (__bf16)__expf(s0[2]); u.b[3] = (__bf16)__expf(s0[3]);
            *reinterpret_cast<short4*>(&p_lds[(oS * 32 + l15) * 8 + sub]) = u.sh;
            u.b[0] = (__bf16)__expf(s1[0]); u.b[1] = (__bf16)__expf(s1[1]);
            u.b[2] = (__bf16)__expf(s1[2]); u.b[3] = (__bf16)__expf(s1[3]);
            *reinterpret_cast<short4*>(&p_lds[(oS * 32 + 16 + l15) * 8 + sub]) = u.sh;
        }
        __syncthreads();   // barrier_B: P visible; nothing outstanding -> cheap

        // ---- issue next tile's DMA (drains at barrier_A of kt+1, hidden under PV)
        if (kt + 1 < kt0 + KT_PER) stage(kt + 1, cur ^ 1);

        // ---- PV phase: wave w owns ch-tiles {2w, 2w+1}
        const int chl = l15 & 7;
        for (int ks = 0; ks < 2; ++ks) {
            int pz = ((ks * 4 + quad) ^ chl);
            bf16x8 a0 = *reinterpret_cast<const bf16x8*>(
                &v_buf[cur][(((2 * w)     * 2 + (l15 >> 3)) * 64 + chl * 8 + pz) * 8]);
            bf16x8 a1 = *reinterpret_cast<const bf16x8*>(
                &v_buf[cur][(((2 * w + 1) * 2 + (l15 >> 3)) * 64 + chl * 8 + pz) * 8]);
            bf16x8 p0 = *reinterpret_cast<const bf16x8*>(
                &p_lds[((ks * 4 + quad) * 32 + 0  + l15) * 8]);
            bf16x8 p1 = *reinterpret_cast<const bf16x8*>(
                &p_lds[((ks * 4 + quad) * 32 + 16 + l15) * 8]);
            acc[0][0] = MFMA(a0, p0, acc[0][0]);
            acc[0][1] = MFMA(a0, p1, acc[0][1]);
            acc[1][0] = MFMA(a1, p0, acc[1][0]);
            acc[1][1] = MFMA(a1, p1, acc[1][1]);
            if (w == 0) {
                lacc[0] = MFMA(ones, p0, lacc[0]);
                lacc[1] = MFMA(ones, p1, lacc[1]);
            }
        }
    }

    // write av partials: av_part[sp][n][c] fp32
    float* dst = av_part + (size_t)sp * 1024000;
    for (int mi = 0; mi < 2; ++mi)
        for (int ni = 0; ni < 2; ++ni) {
            int n  = n0q + ni * 16 + l15;
            int ch = (2 * w + mi) * 16 + quad * 4;
            *reinterpret_cast<f32x4*>(&dst[n * 128 + ch]) = acc[mi][ni];
        }
    if (w == 0 && quad == 0) {
        l_part[sp * N_POS + n0q + 0  + l15] = lacc[0][0];
        l_part[sp * N_POS + n0q + 16 + l15] = lacc[1][0];
    }
}

// ---------------------------------------------------------------------------
// Kernel C: split-K reduce + normalize (fp32, in LDS) fused with
// y = wa @ av + ba (MFMA) + BN stats.  grid 250 (B tile built ONCE per block;
// each wave owns 2 mtiles).
// ---------------------------------------------------------------------------
__global__ __launch_bounds__(256) void proj_out_kernel(
    const float* __restrict__ av_part, const float* __restrict__ l_part,
    const float* __restrict__ wa, const float* __restrict__ ba,
    float* __restrict__ y_ws, float* __restrict__ bn_sum, float* __restrict__ bn_sumsq)
{
    __shared__ __bf16 b_lds[4096];   // 32n x 128c fragment-packed, swizzled

    const int t    = threadIdx.x;
    const int n0   = blockIdx.x * 32;
    const int lane = t & 63;
    const int w    = t >> 6;
    const int l15  = lane & 15;
    const int quad = lane >> 4;

    // build normalized B tile: 512 c-octets, 2 per thread (coalesced reads)
    for (int r = 0; r < 2; ++r) {
        int g = r * 256 + t;
        int n = g >> 4, oc = g & 15;
        float l = 0.f;
#pragma unroll
        for (int s = 0; s < KSPLIT; ++s) l += l_part[s * N_POS + n0 + n];
        float4 a0 = make_float4(0.f, 0.f, 0.f, 0.f);
        float4 a1 = make_float4(0.f, 0.f, 0.f, 0.f);
#pragma unroll
        for (int s = 0; s < KSPLIT; ++s) {
            const float* p = av_part + (size_t)s * 1024000 + (n0 + n) * 128 + oc * 8;
            float4 u = *reinterpret_cast<const float4*>(p);
            float4 v = *reinterpret_cast<const float4*>(p + 4);
            a0.x += u.x; a0.y += u.y; a0.z += u.z; a0.w += u.w;
            a1.x += v.x; a1.y += v.y; a1.z += v.z; a1.w += v.w;
        }
        float inv = 1.f / l;
        union { int4 iv; __bf16 b[8]; } u;
        u.b[0]=(__bf16)(a0.x*inv); u.b[1]=(__bf16)(a0.y*inv);
        u.b[2]=(__bf16)(a0.z*inv); u.b[3]=(__bf16)(a0.w*inv);
        u.b[4]=(__bf16)(a1.x*inv); u.b[5]=(__bf16)(a1.y*inv);
        u.b[6]=(__bf16)(a1.z*inv); u.b[7]=(__bf16)(a1.w*inv);
        int A = (n >> 4) * 16 + oc;
        int slot = (n & 15) ^ (oc & 7);
        *reinterpret_cast<int4*>(&b_lds[(A * 16 + slot) * 8]) = u.iv;
    }

    // A-frags: wa rows for mtiles {2w, 2w+1}
    bf16x8 aw[2][4];
    f32x4  acc[2][2];
    for (int mi = 0; mi < 2; ++mi) {
        int mt = 2 * w + mi;
        const float* wrow = wa + (mt * 16 + l15) * 128;
        for (int ks = 0; ks < 4; ++ks) {
            float4 f0 = *reinterpret_cast<const float4*>(wrow + ks * 32 + quad * 8);
            float4 f1 = *reinterpret_cast<const float4*>(wrow + ks * 32 + quad * 8 + 4);
            bf16x8 a;
            a[0]=(__bf16)f0.x; a[1]=(__bf16)f0.y; a[2]=(__bf16)f0.z; a[3]=(__bf16)f0.w;
            a[4]=(__bf16)f1.x; a[5]=(__bf16)f1.y; a[6]=(__bf16)f1.z; a[7]=(__bf16)f1.w;
            aw[mi][ks] = a;
        }
        for (int ni = 0; ni < 2; ++ni) {
            acc[mi][ni][0] = ba[mt * 16 + quad * 4 + 0];
            acc[mi][ni][1] = ba[mt * 16 + quad * 4 + 1];
            acc[mi][ni][2] = ba[mt * 16 + quad * 4 + 2];
            acc[mi][ni][3] = ba[mt * 16 + quad * 4 + 3];
        }
    }
    __syncthreads();

    for (int ks = 0; ks < 4; ++ks) {
        int oc = ks * 4 + quad;
        int slot = l15 ^ (oc & 7);
        bf16x8 b0 = *reinterpret_cast<const bf16x8*>(&b_lds[((0  + oc) * 16 + slot) * 8]);
        bf16x8 b1 = *reinterpret_cast<const bf16x8*>(&b_lds[((16 + oc) * 16 + slot) * 8]);
        for (int mi = 0; mi < 2; ++mi) {
            acc[mi][0] = MFMA(aw[mi][ks], b0, acc[mi][0]);
            acc[mi][1] = MFMA(aw[mi][ks], b1, acc[mi][1]);
        }
    }

    // y writes [c][n] + BN partial stats
    for (int mi = 0; mi < 2; ++mi) {
        for (int r = 0; r < 4; ++r) {
            int ch = (2 * w + mi) * 16 + quad * 4 + r;
            float v0 = acc[mi][0][r];
            float v1 = acc[mi][1][r];
            y_ws[ch * N_POS + n0 + 0  + l15] = v0;
            y_ws[ch * N_POS + n0 + 16 + l15] = v1;
            float s1 = v0 + v1;
            float s2 = v0 * v0 + v1 * v1;
#pragma unroll
            for (int off = 8; off >= 1; off >>= 1) {
                s1 += __shfl_xor(s1, off, 64);
                s2 += __shfl_xor(s2, off, 64);
            }
            if (l15 == 0) {
                atomicAdd(&bn_sum[ch],   s1);
                atomicAdd(&bn_sumsq[ch], s2);
            }
        }
    }
}

// ---------------------------------------------------------------------------
// Kernel D: BatchNorm (training stats) + ReLU + residual. grid 1000, block 256.
// ---------------------------------------------------------------------------
__global__ __launch_bounds__(256) void bn_relu_kernel(
    const float* __restrict__ y_ws, const float* __restrict__ x,
    const float* __restrict__ bn_sum, const float* __restrict__ bn_sumsq,
    const float* __restrict__ bn_w, const float* __restrict__ bn_b,
    float* __restrict__ out)
{
    const int i4 = blockIdx.x * 256 + threadIdx.x;
    const int c  = i4 / 2000;
    const float mean  = bn_sum[c]   * (1.f / 8000.f);
    const float var   = bn_sumsq[c] * (1.f / 8000.f) - mean * mean;
    const float rstd  = rsqrtf(var + 1e-5f);
    const float scale = bn_w[c] * rstd;
    const float shift = bn_b[c] - mean * scale;

    float4 y4 = reinterpret_cast<const float4*>(y_ws)[i4];
    float4 x4 = reinterpret_cast<const float4*>(x)[i4];
    float4 o4;
    o4.x = fmaxf(y4.x * scale + shift, 0.f) + x4.x;
    o4.y = fmaxf(y4.y * scale + shift, 0.f) + x4.y;
    o4.z = fmaxf(y4.z * scale + shift, 0.f) + x4.z;
    o4.w = fmaxf(y4.w * scale + shift, 0.f) + x4.w;
    reinterpret_cast<float4*>(out)[i4] = o4;
}

// ---------------------------------------------------------------------------
extern "C" void kernel_launch(void* const* d_in, const int* in_sizes, int n_in,
                              void* d_out, int out_size, void* d_ws, size_t ws_size,
                              hipStream_t stream)
{
    const float* x    = (const float*)d_in[0];
    const float* wq   = (const float*)d_in[1];
    const float* bq   = (const float*)d_in[2];
    const float* wk   = (const float*)d_in[3];
    const float* bk   = (const float*)d_in[4];
    const float* wv   = (const float*)d_in[5];
    const float* bv   = (const float*)d_in[6];
    const float* wa   = (const float*)d_in[7];
    const float* ba   = (const float*)d_in[8];
    const float* bn_w = (const float*)d_in[9];
    const float* bn_b = (const float*)d_in[10];
    float* out = (float*)d_out;

    char* base = (char*)d_ws;
    // byte layout (~27.3 MB):
    float*  av_part = (float*)base;                    // 20,480,000 B (5 x 8000 x 128 f32)
    __bf16* q_bf    = (__bf16*)(base + 20480000);      //    256,000 B
    __bf16* k_bf    = (__bf16*)(base + 20736000);      //    256,000 B
    __bf16* v_bf    = (__bf16*)(base + 20992000);      //  2,048,000 B
    float*  l_part  = (float*)(base + 23040000);       //    160,000 B
    float*  bn_sum   = (float*)(base + 23200000);      //        512 B
    float*  bn_sumsq = bn_sum + 128;                   //        512 B
    float*  y_ws    = (float*)(base + 23201024);       //  4,096,000 B

    hipMemsetAsync(bn_sum, 0, 1024, stream);
    qkv_kernel<<<250, 256, 0, stream>>>(x, wq, bq, wk, bk, wv, bv, q_bf, k_bf, v_bf);
    attn_kernel<<<250 * KSPLIT, 256, 0, stream>>>(q_bf, k_bf, v_bf, av_part, l_part);
    proj_out_kernel<<<250, 256, 0, stream>>>(av_part, l_part, wa, ba, y_ws, bn_sum, bn_sumsq);
    bn_relu_kernel<<<1000, 256, 0, stream>>>(y_ws, x, bn_sum, bn_sumsq, bn_w, bn_b, out);
}